// Round 5
// baseline (188.126 us; speedup 1.0000x reference)
//
#include <hip/hip_runtime.h>
#include <hip/hip_bf16.h>
#include <hip/hip_fp16.h>
#include <math.h>

#define NN 50000
#define NE 500000
#define IC 128
#define OC 256
#define NPAD 50176            // 196 * 256
#define NB 196                // node blocks
#define NEB 1954              // edge blocks = ceil(NE/256)
#define NBKT 4                // source buckets (r >> 14): xb slice <= 4.2 MB ~ per-XCD L2
#define CAPB 24               // per-(node,bucket) capacity; Poisson(2.5), P(>=24) ~ 1e-15
#define SLOTS (NBKT * CAPB)   // 96 slots per node

typedef short bf16x8 __attribute__((ext_vector_type(8)));
typedef float f32x4 __attribute__((ext_vector_type(4)));

static __device__ inline unsigned short f2b(float f) {
    __hip_bfloat16 h = __float2bfloat16(f);   // RNE
    return *reinterpret_cast<unsigned short*>(&h);
}
static __device__ inline float b2f(short u) {
    unsigned v = ((unsigned)(unsigned short)u) << 16;
    return __int_as_float(v);
}
static __device__ inline float h2f(unsigned short h) {
    __half v = __ushort_as_half(h);
    return __half2float(v);
}

// ---------------- init: deg = 1.0 (8.24 fixed), bcnt = 0 ----------------
__global__ void k_init(unsigned* __restrict__ deg,
                       uint4* __restrict__ bcnt) {
    int i = blockIdx.x * 256 + threadIdx.x;   // i < NPAD
    deg[i] = 1u << 24;                        // self-loop weight 1
    bcnt[i] = make_uint4(0, 0, 0, 0);
}

// ---------------- pass1: deg atomic (u32 fixed-point, fire-and-forget) +
//                  bucket ordinal atomic; scatter epack[c*96 + b*24 + ord] =
//                  (w:fp16 | row:u16); fused W->WT bf16 conversion ----------------
__global__ void k_pass1(const int* __restrict__ row,
                        const int* __restrict__ col,
                        const float* __restrict__ ew,
                        unsigned* __restrict__ deg,
                        unsigned* __restrict__ bcnt,
                        unsigned* __restrict__ epack,
                        const float* __restrict__ W,
                        unsigned short* __restrict__ WT) {
    int g = blockIdx.x * 256 + threadIdx.x;
    if (g < NE) {
        int c = col[g];
        int r = row[g];
        float w = 1.0f / (1.0f + expf(-ew[g]));   // sigmoid
        atomicAdd(&deg[c], (unsigned)(w * 16777216.0f));
        int b = r >> 14;                          // source bucket 0..3
        unsigned ord = atomicAdd(&bcnt[c * NBKT + b], 1u);
        if (ord < CAPB) {                         // safety clamp (never hit for this data)
            unsigned short wh = __half_as_ushort(__float2half_rn(w));
            unsigned p = ((unsigned)wh << 16) | (unsigned)r;   // row < 65536
            epack[(size_t)c * SLOTS + b * CAPB + ord] = p;
        }
    }
    // fused W -> W^T bf16
    if (g < IC * OC) {
        int k = g >> 8;
        int n = g & 255;
        WT[n * IC + k] = f2b(W[g]);
    }
}

// ---------------- scale: dinv[n] = rsqrt(deg); xb[n] = bf16(x[n] * dinv[n]) ----------------
// Pre-scaling by the SOURCE-side dinv keeps the per-edge work to one fp16 mul.
__global__ __launch_bounds__(256) void k_scale(
        const unsigned* __restrict__ deg,
        const float* __restrict__ x,
        unsigned short* __restrict__ xb,
        float* __restrict__ dinv) {
    int t = threadIdx.x;
    int n = blockIdx.x * 16 + (t >> 4);       // n < 50000 always (3125*16 exact)
    int l = t & 15;
    float dg = (float)deg[n] * (1.0f / 16777216.0f);
    float di = rsqrtf(dg);                    // deg >= 1 always
    if (l == 0) dinv[n] = di;
    const float4* xr = (const float4*)(x + (size_t)n * IC + l * 8);
    float4 a0 = xr[0], a1 = xr[1];
    bf16x8 o;
    o[0] = (short)f2b(a0.x * di); o[1] = (short)f2b(a0.y * di);
    o[2] = (short)f2b(a0.z * di); o[3] = (short)f2b(a0.w * di);
    o[4] = (short)f2b(a1.x * di); o[5] = (short)f2b(a1.y * di);
    o[6] = (short)f2b(a1.z * di); o[7] = (short)f2b(a1.w * di);
    ((bf16x8*)xb)[(size_t)n * 16 + l] = o;
}

// masked edge j of a bucket: slot beyond cnt -> row 0, weight 0 (poison-safe)
#define MEDGE(word, cc, jj, rr, ww)                                          \
    int rr = ((cc) > (jj)) ? (int)((word) & 0xFFFFu) : 0;                    \
    float ww = ((cc) > (jj)) ? h2f((unsigned short)((word) >> 16)) * di : 0.0f;

#define LROW(rr, v0, v1)                                                     \
    bf16x8 v0 = xv[(size_t)(rr) * 16 + l8];                                  \
    bf16x8 v1 = xv[(size_t)(rr) * 16 + 8 + l8];

#define FMAR(v0, v1, ww)                                                     \
    _Pragma("unroll")                                                        \
    for (int c = 0; c < 8; ++c) { acc[c] += b2f(v0[c]) * (ww); acc[8 + c] += b2f(v1[c]) * (ww); }

#define OFLOW(bp, cc)                                                        \
    for (int e = 4; e < (cc); ++e) {                                         \
        unsigned p = (bp)[e];                                                \
        int r_ = (int)(p & 0xFFFFu);                                         \
        float w_ = h2f((unsigned short)(p >> 16)) * di;                      \
        LROW(r_, q0_, q1_)                                                   \
        FMAR(q0_, q1_, w_)                                                   \
    }

// ---------------- fused gather + GEMM ----------------
// 32 nodes per block, 8 lanes per node. Buckets 0..3 walked IN ORDER so the
// whole chip's scattered reads stay inside one <=4.2MB xb slice per phase
// (per-XCD-L2-resident). Buckets processed as 2 pairs, 8 masked head-edges
// staged per pair -> 16 independent row loads in flight per lane.
// Phase B: 4 waves, each 32m x 64n MFMA tile, K=128.
__global__ __launch_bounds__(256) void k_gather_gemm(
        const unsigned short* __restrict__ xb,
        const unsigned* __restrict__ bcnt,
        const unsigned* __restrict__ epack,
        const float* __restrict__ dinv,
        const unsigned short* __restrict__ WT,
        const float* __restrict__ bias,
        float* __restrict__ out) {
    __shared__ __align__(16) unsigned short a[32][136];   // 272B stride: 2-way alias only (free)

    const int base = blockIdx.x * 32;
    const int g = threadIdx.x >> 3;           // node group 0..31
    const int l8 = threadIdx.x & 7;           // owns segments l8 and l8+8 (8 bf16 each)
    const int n = base + g;
    const bf16x8* xv = (const bf16x8*)xb;     // row = 16 units of 8 bf16

    float acc[16];
    if (n < NN) {
        float di = dinv[n];
        uint4 bc = *(const uint4*)(bcnt + (size_t)n * NBKT);
        int c0 = bc.x < CAPB ? (int)bc.x : CAPB;
        int c1 = bc.y < CAPB ? (int)bc.y : CAPB;
        int c2 = bc.z < CAPB ? (int)bc.z : CAPB;
        int c3 = bc.w < CAPB ? (int)bc.w : CAPB;
        const unsigned* ep = epack + (size_t)n * SLOTS;
        uint4 h0 = *(const uint4*)(ep);
        uint4 h1 = *(const uint4*)(ep + CAPB);
        uint4 h2 = *(const uint4*)(ep + 2 * CAPB);
        uint4 h3 = *(const uint4*)(ep + 3 * CAPB);

        // self term: xb[n] = x[n]*di, want x[n]*di^2 -> scale by di
        bf16x8 xs0 = xv[(size_t)n * 16 + l8];
        bf16x8 xs1 = xv[(size_t)n * 16 + 8 + l8];
        #pragma unroll
        for (int c = 0; c < 8; ++c) { acc[c] = b2f(xs0[c]) * di; acc[8 + c] = b2f(xs1[c]) * di; }

        // ---- pair 0: buckets 0,1 (xb rows 0..32767) ----
        {
            MEDGE(h0.x, c0, 0, rA, wA)  MEDGE(h0.y, c0, 1, rB, wB)
            MEDGE(h0.z, c0, 2, rC, wC)  MEDGE(h0.w, c0, 3, rD, wD)
            MEDGE(h1.x, c1, 0, rE, wE)  MEDGE(h1.y, c1, 1, rF, wF)
            MEDGE(h1.z, c1, 2, rG, wG)  MEDGE(h1.w, c1, 3, rH, wH)
            LROW(rA, vA0, vA1)  LROW(rB, vB0, vB1)
            LROW(rC, vC0, vC1)  LROW(rD, vD0, vD1)
            LROW(rE, vE0, vE1)  LROW(rF, vF0, vF1)
            LROW(rG, vG0, vG1)  LROW(rH, vH0, vH1)
            FMAR(vA0, vA1, wA)  FMAR(vB0, vB1, wB)
            FMAR(vC0, vC1, wC)  FMAR(vD0, vD1, wD)
            FMAR(vE0, vE1, wE)  FMAR(vF0, vF1, wF)
            FMAR(vG0, vG1, wG)  FMAR(vH0, vH1, wH)
            if (c0 > 4) { OFLOW(ep, c0) }
            if (c1 > 4) { OFLOW(ep + CAPB, c1) }
        }
        // ---- pair 1: buckets 2,3 (xb rows 32768..49999) ----
        {
            MEDGE(h2.x, c2, 0, rA, wA)  MEDGE(h2.y, c2, 1, rB, wB)
            MEDGE(h2.z, c2, 2, rC, wC)  MEDGE(h2.w, c2, 3, rD, wD)
            MEDGE(h3.x, c3, 0, rE, wE)  MEDGE(h3.y, c3, 1, rF, wF)
            MEDGE(h3.z, c3, 2, rG, wG)  MEDGE(h3.w, c3, 3, rH, wH)
            LROW(rA, vA0, vA1)  LROW(rB, vB0, vB1)
            LROW(rC, vC0, vC1)  LROW(rD, vD0, vD1)
            LROW(rE, vE0, vE1)  LROW(rF, vF0, vF1)
            LROW(rG, vG0, vG1)  LROW(rH, vH0, vH1)
            FMAR(vA0, vA1, wA)  FMAR(vB0, vB1, wB)
            FMAR(vC0, vC1, wC)  FMAR(vD0, vD1, wD)
            FMAR(vE0, vE1, wE)  FMAR(vF0, vF1, wF)
            FMAR(vG0, vG1, wG)  FMAR(vH0, vH1, wH)
            if (c2 > 4) { OFLOW(ep + 2 * CAPB, c2) }
            if (c3 > 4) { OFLOW(ep + 3 * CAPB, c3) }
        }
    } else {
        #pragma unroll
        for (int c = 0; c < 16; ++c) acc[c] = 0.0f;
    }

    bf16x8 o0, o1;
    #pragma unroll
    for (int c = 0; c < 8; ++c) { o0[c] = (short)f2b(acc[c]); o1[c] = (short)f2b(acc[8 + c]); }
    *(bf16x8*)(&a[g][l8 * 8]) = o0;
    *(bf16x8*)(&a[g][64 + l8 * 8]) = o1;

    __syncthreads();

    // --- Phase B: GEMM  out[32m x 256n] = a @ WT^T + bias ---
    const int w = threadIdx.x >> 6;           // wave 0..3 -> n-quadrant
    const int lane = threadIdx.x & 63;
    const int n0 = w * 64;
    const int lm = lane & 15;
    const int lk = (lane >> 4) * 8;

    f32x4 acc4[2][4] = {};
    #pragma unroll
    for (int ks = 0; ks < 4; ++ks) {
        const int k0 = ks * 32 + lk;
        bf16x8 wf[4], af[2];
        #pragma unroll
        for (int j = 0; j < 4; ++j)
            wf[j] = *(const bf16x8*)(WT + (size_t)(n0 + j * 16 + lm) * IC + k0);
        #pragma unroll
        for (int i = 0; i < 2; ++i)
            af[i] = *(const bf16x8*)(&a[i * 16 + lm][k0]);
        #pragma unroll
        for (int i = 0; i < 2; ++i)
            #pragma unroll
            for (int j = 0; j < 4; ++j)
                acc4[i][j] = __builtin_amdgcn_mfma_f32_16x16x32_bf16(wf[j], af[i], acc4[i][j], 0, 0, 0);
    }

    // swapped D layout: col(lane&15) = m-dim, row((lane>>4)*4+reg) = n-dim
    const int mcol = lane & 15;
    const int nb4 = (lane >> 4) * 4;
    #pragma unroll
    for (int i = 0; i < 2; ++i) {
        int m = base + i * 16 + mcol;
        if (m < NN) {
            #pragma unroll
            for (int j = 0; j < 4; ++j) {
                int nn = n0 + j * 16 + nb4;
                float4 bv = *(const float4*)&bias[nn];
                float4 ov;
                ov.x = acc4[i][j][0] + bv.x;
                ov.y = acc4[i][j][1] + bv.y;
                ov.z = acc4[i][j][2] + bv.z;
                ov.w = acc4[i][j][3] + bv.w;
                *(float4*)(out + (size_t)m * OC + nn) = ov;
            }
        }
    }
}

// ---------------- launch ----------------
extern "C" void kernel_launch(void* const* d_in, const int* in_sizes, int n_in,
                              void* d_out, int out_size, void* d_ws, size_t ws_size,
                              hipStream_t stream) {
    const float* x  = (const float*)d_in[0];
    const float* W  = (const float*)d_in[1];
    const float* b  = (const float*)d_in[2];
    const int*   ei = (const int*)d_in[3];
    const float* ew = (const float*)d_in[4];
    const int* row = ei;            // source
    const int* col = ei + NE;       // target
    float* out = (float*)d_out;

    char* w0 = (char*)d_ws;
    unsigned* deg  = (unsigned*)w0;              w0 += NPAD * 4;
    float* dinv  = (float*)w0;                   w0 += NPAD * 4;
    unsigned* bcnt = (unsigned*)w0;              w0 += (size_t)NPAD * NBKT * 4;        // 802 KB
    unsigned* epack = (unsigned*)w0;             w0 += ((size_t)NPAD * SLOTS + 128) * 4; // 19.3 MB + pad
    unsigned short* WT   = (unsigned short*)w0;  w0 += IC * OC * 2;
    unsigned short* xb   = (unsigned short*)w0;  // NN*IC bf16 = 12.8 MB (pre-scaled by dinv)

    k_init       <<<NB, 256, 0, stream>>>(deg, (uint4*)bcnt);
    k_pass1      <<<NEB, 256, 0, stream>>>(row, col, ew, deg, bcnt, epack, W, WT);
    k_scale      <<<NN / 16, 256, 0, stream>>>(deg, x, xb, dinv);
    k_gather_gemm<<<(NN + 31) / 32, 256, 0, stream>>>(xb, bcnt, epack, dinv, WT, b, out);
}

// Round 6
// 181.767 us; speedup vs baseline: 1.0350x; 1.0350x over previous
//
#include <hip/hip_runtime.h>
#include <hip/hip_bf16.h>
#include <hip/hip_fp16.h>
#include <math.h>

#define NN 50000
#define NE 500000
#define IC 128
#define OC 256
#define NPAD 50176            // 196 * 256
#define NB 196                // node blocks
#define NEB 1954              // edge blocks = ceil(NE/256)
#define CAP 64                // CSR bucket capacity per node (Poisson(10) edges/node)
#define NSL 4                 // channel slices (32 ch each): 3.2MB/slice < 4MB per-XCD L2
#define SLICEU ((size_t)NPAD * 32)   // ushorts per slice

typedef short bf16x8 __attribute__((ext_vector_type(8)));
typedef short bf16x4 __attribute__((ext_vector_type(4)));
typedef float f32x4 __attribute__((ext_vector_type(4)));

static __device__ inline unsigned short f2b(float f) {
    __hip_bfloat16 h = __float2bfloat16(f);   // RNE
    return *reinterpret_cast<unsigned short*>(&h);
}
static __device__ inline float b2f(short u) {
    unsigned v = ((unsigned)(unsigned short)u) << 16;
    return __int_as_float(v);
}
static __device__ inline float h2f(unsigned short h) {
    __half v = __ushort_as_half(h);
    return __half2float(v);
}

// ---------------- init: deg64 = (count=0, degfix = 1.0 in 8.24) ----------------
__global__ void k_init(unsigned long long* __restrict__ deg64) {
    int i = blockIdx.x * 256 + threadIdx.x;   // i < NPAD
    deg64[i] = (unsigned long long)(1u << 24);   // self-loop weight 1
}

// ---------------- pass1: single u64 atomic (count|degfix) returns ordinal;
//                  scatter epack[c*CAP+ord] = (w:fp16 | row:u16);
//                  fused W->WT bf16 conversion (r4-proven) ----------------
__global__ void k_pass1(const int* __restrict__ row,
                        const int* __restrict__ col,
                        const float* __restrict__ ew,
                        unsigned long long* __restrict__ deg64,
                        unsigned* __restrict__ epack,
                        const float* __restrict__ W,
                        unsigned short* __restrict__ WT) {
    int g = blockIdx.x * 256 + threadIdx.x;
    if (g < NE) {
        int c = col[g];
        float w = 1.0f / (1.0f + expf(-ew[g]));   // sigmoid
        unsigned long long pack = (1ull << 32) | (unsigned long long)(unsigned)(w * 16777216.0f);
        unsigned long long old = atomicAdd(&deg64[c], pack);
        int ord = (int)(old >> 32);               // within-bucket ordinal
        if (ord < CAP) {                          // safety clamp (never hit for this data)
            unsigned short wh = __half_as_ushort(__float2half_rn(w));
            unsigned p = ((unsigned)wh << 16) | (unsigned)row[g];   // row < 65536
            epack[(size_t)c * CAP + ord] = p;
        }
    }
    // fused W -> W^T bf16
    if (g < IC * OC) {
        int k = g >> 8;
        int n = g & 255;
        WT[n * IC + k] = f2b(W[g]);
    }
}

// ---------------- scale: dinv = rsqrt(deg); xbs[s][n][32] = bf16(x*dinv), sliced ----------------
// Channel-sliced layout: slice s holds channels 32s..32s+31 contiguously
// (64B per node-row) so a gather pass's working set is 3.2MB (< per-XCD L2).
__global__ __launch_bounds__(256) void k_scale(
        const unsigned long long* __restrict__ deg64,
        const float* __restrict__ x,
        unsigned short* __restrict__ xbs,
        float* __restrict__ dinv) {
    int t = threadIdx.x;
    int n = blockIdx.x * 16 + (t >> 4);       // n < 50000 always (3125*16 exact)
    int l = t & 15;                           // channels 8l..8l+7 -> slice l>>2
    unsigned long long v = deg64[n];
    float deg = (float)(unsigned)v * (1.0f / 16777216.0f);
    float di = rsqrtf(deg);                   // deg >= 1 always
    if (l == 0) dinv[n] = di;
    const float4* xr = (const float4*)(x + (size_t)n * IC + l * 8);
    float4 a0 = xr[0], a1 = xr[1];
    bf16x8 o;
    o[0] = (short)f2b(a0.x * di); o[1] = (short)f2b(a0.y * di);
    o[2] = (short)f2b(a0.z * di); o[3] = (short)f2b(a0.w * di);
    o[4] = (short)f2b(a1.x * di); o[5] = (short)f2b(a1.y * di);
    o[6] = (short)f2b(a1.z * di); o[7] = (short)f2b(a1.w * di);
    *(bf16x8*)(xbs + (size_t)(l >> 2) * SLICEU + (size_t)n * 32 + (l & 3) * 8) = o;
}

// ---------------- gather pass s: agg slice = self + sum_e xbs[s][r]*w*di ----------------
// Launch boundary = chip-wide sync: during pass s ALL scattered reads hit one
// 3.2MB xb slice -> per-XCD-L2 resident. 32 nodes/block, 8 lanes/node, 8B row
// loads (one 64B line per node-row per group), r4's unroll-4 + uint4 prefetch.
__global__ __launch_bounds__(256) void k_gather(
        const unsigned short* __restrict__ xbs,
        const unsigned long long* __restrict__ deg64,
        const unsigned* __restrict__ epack,
        const float* __restrict__ dinv,
        unsigned short* __restrict__ aggs,
        int s) {
    const int base = blockIdx.x * 32;
    const int g = threadIdx.x >> 3;           // node group 0..31
    const int l8 = threadIdx.x & 7;           // 4 channels: l8*4 .. l8*4+3
    const int n = base + g;
    if (n >= NN) return;                      // no LDS/sync in this kernel

    const unsigned short* xsl = xbs + (size_t)s * SLICEU;
    float di = dinv[n];
    unsigned long long dv = deg64[n];
    int cnt = (int)(dv >> 32);
    if (cnt > CAP) cnt = CAP;

    // self term: xsl row is x[n]*di, want x[n]*di^2 -> scale by di
    bf16x4 xs = *(const bf16x4*)(xsl + (size_t)n * 32 + l8 * 4);
    float acc[4];
    #pragma unroll
    for (int c = 0; c < 4; ++c) acc[c] = b2f(xs[c]) * di;

    const unsigned* ep = epack + (size_t)n * CAP;
    uint4 q = *(const uint4*)ep;              // descriptors for group 0
    int e = 0;
    for (; e + 4 <= cnt; e += 4) {
        uint4 cur = q;
        q = *(const uint4*)(ep + e + 4);      // prefetch next group (overread safe: pad)
        int r0 = (int)(cur.x & 0xFFFFu);
        int r1 = (int)(cur.y & 0xFFFFu);
        int r2 = (int)(cur.z & 0xFFFFu);
        int r3 = (int)(cur.w & 0xFFFFu);
        float w0 = h2f((unsigned short)(cur.x >> 16)) * di;
        float w1 = h2f((unsigned short)(cur.y >> 16)) * di;
        float w2 = h2f((unsigned short)(cur.z >> 16)) * di;
        float w3 = h2f((unsigned short)(cur.w >> 16)) * di;
        bf16x4 v0 = *(const bf16x4*)(xsl + (size_t)r0 * 32 + l8 * 4);
        bf16x4 v1 = *(const bf16x4*)(xsl + (size_t)r1 * 32 + l8 * 4);
        bf16x4 v2 = *(const bf16x4*)(xsl + (size_t)r2 * 32 + l8 * 4);
        bf16x4 v3 = *(const bf16x4*)(xsl + (size_t)r3 * 32 + l8 * 4);
        #pragma unroll
        for (int c = 0; c < 4; ++c) acc[c] += b2f(v0[c]) * w0;
        #pragma unroll
        for (int c = 0; c < 4; ++c) acc[c] += b2f(v1[c]) * w1;
        #pragma unroll
        for (int c = 0; c < 4; ++c) acc[c] += b2f(v2[c]) * w2;
        #pragma unroll
        for (int c = 0; c < 4; ++c) acc[c] += b2f(v3[c]) * w3;
    }
    for (; e < cnt; ++e) {                    // tail 0-3 edges, lines already hot
        unsigned p = ep[e];
        int r = (int)(p & 0xFFFFu);
        float w = h2f((unsigned short)(p >> 16)) * di;
        bf16x4 v = *(const bf16x4*)(xsl + (size_t)r * 32 + l8 * 4);
        #pragma unroll
        for (int c = 0; c < 4; ++c) acc[c] += b2f(v[c]) * w;
    }

    bf16x4 o;
    #pragma unroll
    for (int c = 0; c < 4; ++c) o[c] = (short)f2b(acc[c]);
    *(bf16x4*)(aggs + (size_t)s * SLICEU + (size_t)n * 32 + l8 * 4) = o;
}

// ---------------- GEMM: out = agg @ WT^T + b (r0-proven shape, sliced A reads) ----------------
// block 256 = 4 waves; block tile 64m x 128n; wave tile 32m x 64n; grid (2, 782)
__global__ __launch_bounds__(256) void k_gemm(const unsigned short* __restrict__ aggs,
                                              const unsigned short* __restrict__ WT,
                                              const float* __restrict__ bias,
                                              float* __restrict__ out) {
    const int w = threadIdx.x >> 6;
    const int lane = threadIdx.x & 63;
    const int m0 = blockIdx.y * 64 + (w >> 1) * 32;
    const int n0 = blockIdx.x * 128 + (w & 1) * 64;
    const int lm = lane & 15;
    const int lk = (lane >> 4) * 8;

    f32x4 acc[2][4] = {};
    #pragma unroll
    for (int ks = 0; ks < 4; ++ks) {          // ks selects K-range 32ks.. = slice ks
        bf16x8 wf[4], af[2];
        #pragma unroll
        for (int j = 0; j < 4; ++j)
            wf[j] = *(const bf16x8*)(WT + (size_t)(n0 + j * 16 + lm) * IC + ks * 32 + lk);
        #pragma unroll
        for (int i = 0; i < 2; ++i)
            af[i] = *(const bf16x8*)(aggs + (size_t)ks * SLICEU + (size_t)(m0 + i * 16 + lm) * 32 + lk);
        #pragma unroll
        for (int i = 0; i < 2; ++i)
            #pragma unroll
            for (int j = 0; j < 4; ++j)
                acc[i][j] = __builtin_amdgcn_mfma_f32_16x16x32_bf16(wf[j], af[i], acc[i][j], 0, 0, 0);
    }

    // swapped D layout: col(lane&15) = m-dim, row((lane>>4)*4+reg) = n-dim
    const int mcol = lane & 15;
    const int nb4 = (lane >> 4) * 4;
    #pragma unroll
    for (int i = 0; i < 2; ++i) {
        int m = m0 + i * 16 + mcol;
        if (m < NN) {
            #pragma unroll
            for (int j = 0; j < 4; ++j) {
                int nn = n0 + j * 16 + nb4;
                float4 bv = *(const float4*)&bias[nn];
                float4 o;
                o.x = acc[i][j][0] + bv.x;
                o.y = acc[i][j][1] + bv.y;
                o.z = acc[i][j][2] + bv.z;
                o.w = acc[i][j][3] + bv.w;
                *(float4*)(out + (size_t)m * OC + nn) = o;
            }
        }
    }
}

// ---------------- launch ----------------
extern "C" void kernel_launch(void* const* d_in, const int* in_sizes, int n_in,
                              void* d_out, int out_size, void* d_ws, size_t ws_size,
                              hipStream_t stream) {
    const float* x  = (const float*)d_in[0];
    const float* W  = (const float*)d_in[1];
    const float* b  = (const float*)d_in[2];
    const int*   ei = (const int*)d_in[3];
    const float* ew = (const float*)d_in[4];
    const int* row = ei;            // source
    const int* col = ei + NE;       // target
    float* out = (float*)d_out;

    char* w0 = (char*)d_ws;
    unsigned long long* deg64 = (unsigned long long*)w0;  w0 += NPAD * 8;
    float* dinv  = (float*)w0;                   w0 += NPAD * 4;
    unsigned* epack = (unsigned*)w0;             w0 += ((size_t)NPAD * CAP + 128) * 4;  // 12.9 MB + pad
    unsigned short* WT   = (unsigned short*)w0;  w0 += IC * OC * 2;
    unsigned short* xbs  = (unsigned short*)w0;  w0 += NSL * SLICEU * 2;   // 12.85 MB sliced
    unsigned short* aggs = (unsigned short*)w0;  // NSL * SLICEU bf16 = 12.85 MB sliced

    k_init  <<<NB, 256, 0, stream>>>(deg64);
    k_pass1 <<<NEB, 256, 0, stream>>>(row, col, ew, deg64, epack, W, WT);
    k_scale <<<NN / 16, 256, 0, stream>>>(deg64, x, xbs, dinv);
    for (int s = 0; s < NSL; ++s)
        k_gather<<<(NN + 31) / 32, 256, 0, stream>>>(xbs, deg64, epack, dinv, aggs, s);
    k_gemm  <<<dim3(2, (NN + 63) / 64), 256, 0, stream>>>(aggs, WT, b, out);
}

// Round 8
// 161.158 us; speedup vs baseline: 1.1673x; 1.1279x over previous
//
#include <hip/hip_runtime.h>
#include <hip/hip_bf16.h>
#include <hip/hip_fp16.h>
#include <math.h>

#define NN 50000
#define NE 500000
#define IC 128
#define OC 256
#define NPAD 50176            // 196 * 256
#define NEB 1954              // edge blocks = ceil(NE/256)
#define CAP 64                // CSR bucket capacity per node (Poisson(10) edges/node)

typedef short bf16x8 __attribute__((ext_vector_type(8)));
typedef float f32x4 __attribute__((ext_vector_type(4)));

static __device__ inline unsigned short f2b(float f) {
    __hip_bfloat16 h = __float2bfloat16(f);   // RNE
    return *reinterpret_cast<unsigned short*>(&h);
}
static __device__ inline float b2f(short u) {
    unsigned v = ((unsigned)(unsigned short)u) << 16;
    return __int_as_float(v);
}
static __device__ inline float h2f(unsigned short h) {
    __half v = __ushort_as_half(h);
    return __half2float(v);
}
// deg64 low 32 = sum(sigmoid(w)) in 8.24 fixed (EXCLUDING self-loop; buffer is
// memset-0), high 32 = edge count. Same decode everywhere -> bit-identical di.
static __device__ inline float deg_to_di(unsigned long long dv) {
    return rsqrtf((float)(unsigned)dv * (1.0f / 16777216.0f) + 1.0f);
}

// ---------------- pass1: single u64 atomic (count|degfix) returns ordinal;
//                  scatter epack[c*CAP+ord] = (w:fp16 | row:u16);
//                  fused W->WT bf16 conversion ----------------
__global__ void k_pass1(const int* __restrict__ row,
                        const int* __restrict__ col,
                        const float* __restrict__ ew,
                        unsigned long long* __restrict__ deg64,
                        unsigned* __restrict__ epack,
                        const float* __restrict__ W,
                        unsigned short* __restrict__ WT) {
    int g = blockIdx.x * 256 + threadIdx.x;
    if (g < NE) {
        int c = col[g];
        float w = 1.0f / (1.0f + expf(-ew[g]));   // sigmoid
        unsigned long long pack = (1ull << 32) | (unsigned long long)(unsigned)(w * 16777216.0f);
        unsigned long long old = atomicAdd(&deg64[c], pack);
        int ord = (int)(old >> 32);               // within-bucket ordinal
        if (ord < CAP) {                          // safety clamp (never hit for this data)
            unsigned short wh = __half_as_ushort(__float2half_rn(w));
            unsigned p = ((unsigned)wh << 16) | (unsigned)row[g];   // row < 65536
            epack[(size_t)c * CAP + ord] = p;
        }
    }
    // fused W -> W^T bf16
    if (g < IC * OC) {
        int k = g >> 8;
        int n = g & 255;
        WT[n * IC + k] = f2b(W[g]);
    }
}

// ---------------- scale: xb[n] = bf16(x[n] * rsqrt(deg[n])) ----------------
// Pre-scaling by the SOURCE-side dinv removes the per-edge random dinv[r]
// load (and one dependency hop) from the latency-bound gather.
__global__ __launch_bounds__(256) void k_scale(
        const unsigned long long* __restrict__ deg64,
        const float* __restrict__ x,
        unsigned short* __restrict__ xb) {
    int t = threadIdx.x;
    int n = blockIdx.x * 16 + (t >> 4);       // n < 50000 always (3125*16 exact)
    int l = t & 15;
    float di = deg_to_di(deg64[n]);
    const float4* xr = (const float4*)(x + (size_t)n * IC + l * 8);
    float4 a0 = xr[0], a1 = xr[1];
    bf16x8 o;
    o[0] = (short)f2b(a0.x * di); o[1] = (short)f2b(a0.y * di);
    o[2] = (short)f2b(a0.z * di); o[3] = (short)f2b(a0.w * di);
    o[4] = (short)f2b(a1.x * di); o[5] = (short)f2b(a1.y * di);
    o[6] = (short)f2b(a1.z * di); o[7] = (short)f2b(a1.w * di);
    ((bf16x8*)xb)[(size_t)n * 16 + l] = o;
}

// ---------------- fused gather + GEMM (r4-proven shape) ----------------
// 32 nodes per block, 8 lanes per node. uint4 descriptor prefetch one group
// ahead + unroll-4 -> 8 independent 16B row loads in flight per lane,
// descriptors always ready before row-load issue (VMEM completes in order).
// At the scattered-sector wall: 2M 64B sectors @ ~44G/s. Phase B: 4 waves,
// each 32m x 64n MFMA tile, K=128.
__global__ __launch_bounds__(256) void k_gather_gemm(
        const unsigned short* __restrict__ xb,
        const unsigned long long* __restrict__ deg64,
        const unsigned* __restrict__ epack,
        const unsigned short* __restrict__ WT,
        const float* __restrict__ bias,
        float* __restrict__ out) {
    __shared__ __align__(16) unsigned short a[32][136];   // 272B stride: 2-way alias only (free)

    const int base = blockIdx.x * 32;
    const int g = threadIdx.x >> 3;           // node group 0..31
    const int l8 = threadIdx.x & 7;           // owns segments l8 and l8+8 (8 bf16 each)
    const int n = base + g;
    const bf16x8* xv = (const bf16x8*)xb;     // row = 16 units of 8 bf16

    float acc[16];
    if (n < NN) {
        unsigned long long dv = deg64[n];
        float di = deg_to_di(dv);
        int cnt = (int)(dv >> 32);
        if (cnt > CAP) cnt = CAP;

        // self term: xb[n] = x[n]*di, want x[n]*di^2 -> scale by di
        bf16x8 xs0 = xv[(size_t)n * 16 + l8];
        bf16x8 xs1 = xv[(size_t)n * 16 + 8 + l8];
        #pragma unroll
        for (int c = 0; c < 8; ++c) { acc[c] = b2f(xs0[c]) * di; acc[8 + c] = b2f(xs1[c]) * di; }

        const unsigned* ep = epack + (size_t)n * CAP;
        uint4 q = *(const uint4*)ep;          // descriptors for group 0
        int e = 0;
        for (; e + 4 <= cnt; e += 4) {
            uint4 cur = q;
            q = *(const uint4*)(ep + e + 4);  // prefetch next group (overread safe: pad)
            int r0 = (int)(cur.x & 0xFFFFu);
            int r1 = (int)(cur.y & 0xFFFFu);
            int r2 = (int)(cur.z & 0xFFFFu);
            int r3 = (int)(cur.w & 0xFFFFu);
            float w0 = h2f((unsigned short)(cur.x >> 16)) * di;
            float w1 = h2f((unsigned short)(cur.y >> 16)) * di;
            float w2 = h2f((unsigned short)(cur.z >> 16)) * di;
            float w3 = h2f((unsigned short)(cur.w >> 16)) * di;
            bf16x8 v00 = xv[(size_t)r0 * 16 + l8];
            bf16x8 v01 = xv[(size_t)r0 * 16 + 8 + l8];
            bf16x8 v10 = xv[(size_t)r1 * 16 + l8];
            bf16x8 v11 = xv[(size_t)r1 * 16 + 8 + l8];
            bf16x8 v20 = xv[(size_t)r2 * 16 + l8];
            bf16x8 v21 = xv[(size_t)r2 * 16 + 8 + l8];
            bf16x8 v30 = xv[(size_t)r3 * 16 + l8];
            bf16x8 v31 = xv[(size_t)r3 * 16 + 8 + l8];
            #pragma unroll
            for (int c = 0; c < 8; ++c) { acc[c] += b2f(v00[c]) * w0; acc[8 + c] += b2f(v01[c]) * w0; }
            #pragma unroll
            for (int c = 0; c < 8; ++c) { acc[c] += b2f(v10[c]) * w1; acc[8 + c] += b2f(v11[c]) * w1; }
            #pragma unroll
            for (int c = 0; c < 8; ++c) { acc[c] += b2f(v20[c]) * w2; acc[8 + c] += b2f(v21[c]) * w2; }
            #pragma unroll
            for (int c = 0; c < 8; ++c) { acc[c] += b2f(v30[c]) * w3; acc[8 + c] += b2f(v31[c]) * w3; }
        }
        for (; e < cnt; ++e) {                // tail 0-3 edges, lines already hot
            unsigned p = ep[e];
            int r = (int)(p & 0xFFFFu);
            float w = h2f((unsigned short)(p >> 16)) * di;
            bf16x8 v0 = xv[(size_t)r * 16 + l8];
            bf16x8 v1 = xv[(size_t)r * 16 + 8 + l8];
            #pragma unroll
            for (int c = 0; c < 8; ++c) { acc[c] += b2f(v0[c]) * w; acc[8 + c] += b2f(v1[c]) * w; }
        }
    } else {
        #pragma unroll
        for (int c = 0; c < 16; ++c) acc[c] = 0.0f;
    }

    bf16x8 o0, o1;
    #pragma unroll
    for (int c = 0; c < 8; ++c) { o0[c] = (short)f2b(acc[c]); o1[c] = (short)f2b(acc[8 + c]); }
    *(bf16x8*)(&a[g][l8 * 8]) = o0;
    *(bf16x8*)(&a[g][64 + l8 * 8]) = o1;

    __syncthreads();

    // --- Phase B: GEMM  out[32m x 256n] = a @ WT^T + bias ---
    const int w = threadIdx.x >> 6;           // wave 0..3 -> n-quadrant
    const int lane = threadIdx.x & 63;
    const int n0 = w * 64;
    const int lm = lane & 15;
    const int lk = (lane >> 4) * 8;

    f32x4 acc4[2][4] = {};
    #pragma unroll
    for (int ks = 0; ks < 4; ++ks) {
        const int k0 = ks * 32 + lk;
        bf16x8 wf[4], af[2];
        #pragma unroll
        for (int j = 0; j < 4; ++j)
            wf[j] = *(const bf16x8*)(WT + (size_t)(n0 + j * 16 + lm) * IC + k0);
        #pragma unroll
        for (int i = 0; i < 2; ++i)
            af[i] = *(const bf16x8*)(&a[i * 16 + lm][k0]);
        #pragma unroll
        for (int i = 0; i < 2; ++i)
            #pragma unroll
            for (int j = 0; j < 4; ++j)
                acc4[i][j] = __builtin_amdgcn_mfma_f32_16x16x32_bf16(wf[j], af[i], acc4[i][j], 0, 0, 0);
    }

    // swapped D layout: col(lane&15) = m-dim, row((lane>>4)*4+reg) = n-dim
    const int mcol = lane & 15;
    const int nb4 = (lane >> 4) * 4;
    #pragma unroll
    for (int i = 0; i < 2; ++i) {
        int m = base + i * 16 + mcol;
        if (m < NN) {
            #pragma unroll
            for (int j = 0; j < 4; ++j) {
                int nn = n0 + j * 16 + nb4;
                float4 bv = *(const float4*)&bias[nn];
                float4 ov;
                ov.x = acc4[i][j][0] + bv.x;
                ov.y = acc4[i][j][1] + bv.y;
                ov.z = acc4[i][j][2] + bv.z;
                ov.w = acc4[i][j][3] + bv.w;
                *(float4*)(out + (size_t)m * OC + nn) = ov;
            }
        }
    }
}

// ---------------- launch ----------------
extern "C" void kernel_launch(void* const* d_in, const int* in_sizes, int n_in,
                              void* d_out, int out_size, void* d_ws, size_t ws_size,
                              hipStream_t stream) {
    const float* x  = (const float*)d_in[0];
    const float* W  = (const float*)d_in[1];
    const float* b  = (const float*)d_in[2];
    const int*   ei = (const int*)d_in[3];
    const float* ew = (const float*)d_in[4];
    const int* row = ei;            // source
    const int* col = ei + NE;       // target
    float* out = (float*)d_out;

    char* w0 = (char*)d_ws;
    unsigned long long* deg64 = (unsigned long long*)w0;  w0 += NPAD * 8;
    unsigned* epack = (unsigned*)w0;             w0 += ((size_t)NPAD * CAP + 128) * 4;  // 12.9 MB + pad
    unsigned short* WT   = (unsigned short*)w0;  w0 += IC * OC * 2;
    unsigned short* xb   = (unsigned short*)w0;  // NN*IC bf16 = 12.8 MB (pre-scaled by dinv)

    hipMemsetAsync(deg64, 0, NPAD * 8, stream);   // deg = self-loop-excluded 0; +1.0 in decode
    k_pass1      <<<NEB, 256, 0, stream>>>(row, col, ew, deg64, epack, W, WT);
    k_scale      <<<NN / 16, 256, 0, stream>>>(deg64, x, xb);
    k_gather_gemm<<<(NN + 31) / 32, 256, 0, stream>>>(xb, deg64, epack, WT, b, out);
}